// Round 1
// baseline (501.690 us; speedup 1.0000x reference)
//
#include <hip/hip_runtime.h>

#define N_NODES 40000
#define N_EDGES 640000
#define F_INW 128
#define HIDW 256
#define OUTW_D 128
#define NGRAPH 64

typedef unsigned short u16;
typedef unsigned int u32;
typedef __attribute__((ext_vector_type(4))) float floatx4;
typedef __attribute__((ext_vector_type(8))) short short8;
typedef __attribute__((ext_vector_type(8))) __bf16 bf16x8;

__device__ __forceinline__ float bf2f(u16 u) {
  u32 x = ((u32)u) << 16;
  return __builtin_bit_cast(float, x);
}
__device__ __forceinline__ u16 f2bf(float f) {
  u32 u = __builtin_bit_cast(u32, f);
  u += 0x7fffu + ((u >> 16) & 1u);   // RNE
  return (u16)(u >> 16);
}
__device__ __forceinline__ void gld16(const void* g, void* l) {
  __builtin_amdgcn_global_load_lds(
      (const __attribute__((address_space(1))) u32*)g,
      (__attribute__((address_space(3))) u32*)l, 16, 0, 0);
}

// ---------------- CSR build ----------------
__global__ void k_zero(int* p, int n) {
  int i = blockIdx.x * 256 + threadIdx.x;
  if (i < n) p[i] = 0;
}
__global__ void k_hist(const int* __restrict__ ei, int* __restrict__ cnt) {
  int e = blockIdx.x * 256 + threadIdx.x;
  int d = ei[N_EDGES + e];
  atomicAdd(&cnt[d], 1);
}
__global__ void k_blocksum(const int* __restrict__ cnt, int* __restrict__ bsum, int n) {
  __shared__ int s[256];
  int t = threadIdx.x, i = blockIdx.x * 256 + t;
  s[t] = (i < n) ? cnt[i] : 0;
  __syncthreads();
  for (int off = 128; off > 0; off >>= 1) {
    if (t < off) s[t] += s[t + off];
    __syncthreads();
  }
  if (t == 0) bsum[blockIdx.x] = s[0];
}
__global__ void k_scan_small(int* bsum, int n) {
  if (threadIdx.x == 0 && blockIdx.x == 0) {
    int run = 0;
    for (int i = 0; i < n; ++i) { int v = bsum[i]; bsum[i] = run; run += v; }
  }
}
__global__ void k_rowptr(const int* __restrict__ cnt, const int* __restrict__ bsum,
                         int* __restrict__ rowptr, float* __restrict__ invc, int n, int total) {
  __shared__ int s[256];
  int t = threadIdx.x, i = blockIdx.x * 256 + t;
  int c = (i < n) ? cnt[i] : 0;
  s[t] = c;
  __syncthreads();
  for (int off = 1; off < 256; off <<= 1) {
    int v = (t >= off) ? s[t - off] : 0;
    __syncthreads();
    s[t] += v;
    __syncthreads();
  }
  if (i < n) {
    rowptr[i] = bsum[blockIdx.x] + s[t] - c;   // exclusive
    invc[i] = 1.0f / (float)(c > 1 ? c : 1);
  }
  if (i == 0) rowptr[n] = total;
}
__global__ void k_scatter(const int* __restrict__ ei, const int* __restrict__ rowptr,
                          int* __restrict__ cursor, int* __restrict__ perm) {
  int e = blockIdx.x * 256 + threadIdx.x;
  int d = ei[N_EDGES + e];
  int srcn = ei[e];
  int pos = rowptr[d] + atomicAdd(&cursor[d], 1);
  perm[pos] = srcn;
}
__global__ void k_gstart(const int* __restrict__ batch, int* __restrict__ gstart) {
  int t = threadIdx.x;
  if (t <= NGRAPH) {
    int lo = 0, hi = N_NODES;
    while (lo < hi) { int mid = (lo + hi) >> 1; if (batch[mid] < t) lo = mid + 1; else hi = mid; }
    gstart[t] = lo;
  }
}

// ---------------- f32 -> bf16 convert ----------------
__global__ void k_f2b(const float* __restrict__ in, u16* __restrict__ out, int n4) {
  int i = blockIdx.x * 256 + threadIdx.x;
  if (i < n4) {
    float4 v = ((const float4*)in)[i];
    u32 lo = (u32)f2bf(v.x) | ((u32)f2bf(v.y) << 16);
    u32 hi = (u32)f2bf(v.z) | ((u32)f2bf(v.w) << 16);
    ((uint2*)out)[i] = make_uint2(lo, hi);
  }
}

// ---------------- CSR mean aggregation ----------------
// one wave per dst node; bf16 in, f32 accum, bf16 or f32 out
template <int D, int F32OUT>
__global__ __launch_bounds__(256) void k_agg(const u16* __restrict__ x, void* __restrict__ outp,
                                             const int* __restrict__ rowptr,
                                             const int* __restrict__ perm,
                                             const float* __restrict__ invc, int nn) {
  int wv = threadIdx.x >> 6, lane = threadIdx.x & 63;
  int node = blockIdx.x * 4 + wv;
  if (node >= nn) return;
  int s = rowptr[node], e = rowptr[node + 1];
  constexpr int CP = D / 64;  // cols per lane: 2 (D=128) or 4 (D=256)
  float acc[CP];
#pragma unroll
  for (int i = 0; i < CP; ++i) acc[i] = 0.f;
  for (int p = s; p < e; ++p) {
    int src = perm[p];
    const u16* rp = x + (size_t)src * D + lane * CP;
    if (CP == 2) {
      u32 v = *(const u32*)rp;
      acc[0] += bf2f((u16)(v & 0xffff));
      acc[1] += bf2f((u16)(v >> 16));
    } else {
      uint2 v = *(const uint2*)rp;
      acc[0] += bf2f((u16)(v.x & 0xffff));
      acc[1] += bf2f((u16)(v.x >> 16));
      acc[2] += bf2f((u16)(v.y & 0xffff));
      acc[3] += bf2f((u16)(v.y >> 16));
    }
  }
  float iv = invc[node];
  if (F32OUT) {
    float* o = (float*)outp + (size_t)node * D + lane * CP;
    if (CP == 2) {
      ((float2*)o)[0] = make_float2(acc[0] * iv, acc[1] * iv);
    } else {
      ((float4*)o)[0] = make_float4(acc[0] * iv, acc[1] * iv, acc[2] * iv, acc[3] * iv);
    }
  } else {
    u16* o = (u16*)outp + (size_t)node * D + lane * CP;
    if (CP == 2) {
      u32 v = (u32)f2bf(acc[0] * iv) | ((u32)f2bf(acc[1] * iv) << 16);
      *(u32*)o = v;
    } else {
      u32 a = (u32)f2bf(acc[0] * iv) | ((u32)f2bf(acc[1] * iv) << 16);
      u32 b = (u32)f2bf(acc[2] * iv) | ((u32)f2bf(acc[3] * iv) << 16);
      *(uint2*)o = make_uint2(a, b);
    }
  }
}

// ---------------- bf16 MFMA GEMM:  out = epilogue(A1@W1^T + A2@W2^T) ----------------
// A: [M,K] bf16 row-major; W: [OUTW,K] bf16 row-major. 128x128 tile, 4 waves x (64x64).
// EPI: 0 = +bias, relu, ->bf16 ; 1 = plain ->bf16 ; 2 = +bias +agg ->f32
template <int OUTW, int EPI>
__global__ __launch_bounds__(256) void k_gemm(const u16* __restrict__ A1, const u16* __restrict__ W1, int K1,
                                              const u16* __restrict__ A2, const u16* __restrict__ W2, int K2,
                                              const float* __restrict__ bias,
                                              const float* __restrict__ aggadd,
                                              void* __restrict__ outp, int M) {
  __shared__ u16 lsA[128 * 64];
  __shared__ u16 lsB[128 * 64];
  const int tid = threadIdx.x, lane = tid & 63, wv = tid >> 6;
  const int wm = wv >> 1, wn = wv & 1;
  const int row0 = blockIdx.x * 128, col0 = blockIdx.y * 128;

  floatx4 acc[4][4];
#pragma unroll
  for (int r = 0; r < 4; ++r)
#pragma unroll
    for (int c = 0; c < 4; ++c) acc[r][c] = 0.f;

  for (int seg = 0; seg < 2; ++seg) {
    const u16* A = seg ? A2 : A1;
    const u16* Wm = seg ? W2 : W1;
    const int K = seg ? K2 : K1;
    if (K == 0) continue;
    for (int k0 = 0; k0 < K; k0 += 64) {
      __syncthreads();  // protect LDS from overwrite while previous compute reads
      // stage A tile [128 rows x 64 k] and B tile (W rows) with XOR-swizzled source
#pragma unroll
      for (int i = 0; i < 4; ++i) {
        int chunk = i * 256 + tid;
        int r = chunk >> 3;            // 0..127
        int kc = chunk & 7;            // 16B chunk in row
        int kcs = kc ^ (r & 7);        // pre-swizzle the SOURCE (linear LDS dest)
        int grow = row0 + r;
        grow = grow < M ? grow : M - 1;
        gld16(A + (size_t)grow * K + (k0 + kcs * 8), lsA + (size_t)(i * 256 + wv * 64) * 8);
        int wr = col0 + r;             // always < OUTW
        gld16(Wm + (size_t)wr * K + (k0 + kcs * 8), lsB + (size_t)(i * 256 + wv * 64) * 8);
      }
      __syncthreads();  // compiler drains vmcnt before barrier
#pragma unroll
      for (int kk = 0; kk < 2; ++kk) {
        bf16x8 af[4], bb[4];
        int kc = kk * 4 + (lane >> 4);
#pragma unroll
        for (int r = 0; r < 4; ++r) {
          int row = wm * 64 + r * 16 + (lane & 15);
          af[r] = __builtin_bit_cast(bf16x8, *(const short8*)(lsA + row * 64 + ((kc ^ (row & 7)) << 3)));
        }
#pragma unroll
        for (int c = 0; c < 4; ++c) {
          int row = wn * 64 + c * 16 + (lane & 15);
          bb[c] = __builtin_bit_cast(bf16x8, *(const short8*)(lsB + row * 64 + ((kc ^ (row & 7)) << 3)));
        }
#pragma unroll
        for (int r = 0; r < 4; ++r)
#pragma unroll
          for (int c = 0; c < 4; ++c)
            acc[r][c] = __builtin_amdgcn_mfma_f32_16x16x32_bf16(af[r], bb[c], acc[r][c], 0, 0, 0);
      }
    }
  }

  // epilogue: C[row = (lane>>4)*4+j, col = lane&15] per fragment (m89-verified layout)
  u16* ob = (u16*)outp;
  float* of = (float*)outp;
#pragma unroll
  for (int r = 0; r < 4; ++r) {
    int rowb = row0 + wm * 64 + r * 16 + ((lane >> 4) << 2);
#pragma unroll
    for (int c = 0; c < 4; ++c) {
      int col = col0 + wn * 64 + c * 16 + (lane & 15);
#pragma unroll
      for (int j = 0; j < 4; ++j) {
        int gr = rowb + j;
        if (gr < M) {
          float v = acc[r][c][j];
          if (EPI == 0) {
            v += bias[col];
            v = v > 0.f ? v : 0.f;
            ob[(size_t)gr * OUTW + col] = f2bf(v);
          } else if (EPI == 1) {
            ob[(size_t)gr * OUTW + col] = f2bf(v);
          } else {
            v += bias[col] + aggadd[(size_t)gr * OUTW + col];
            of[(size_t)gr * OUTW + col] = v;
          }
        }
      }
    }
  }
}

// ---------------- global mean pool (batch sorted -> contiguous ranges) ----------------
__global__ __launch_bounds__(256) void k_pool(const float* __restrict__ h3, const int* __restrict__ gstart,
                                              float* __restrict__ gv_ws, float* __restrict__ dout) {
  __shared__ float red[256];
  int b = blockIdx.x, t = threadIdx.x;
  int col = t & 127, sub = t >> 7;
  int s = gstart[b], e = gstart[b + 1];
  float acc = 0.f;
  for (int n = s + sub; n < e; n += 2) acc += h3[(size_t)n * 128 + col];
  red[t] = acc;
  __syncthreads();
  if (sub == 0) {
    int cg = e - s;
    float mean = (red[col] + red[128 + col]) / (float)(cg > 1 ? cg : 1);
    gv_ws[b * 128 + col] = mean;
    dout[b * 128 + col] = mean;  // output 0
  }
}

// ---------------- per-graph tail: v-proj chain + LayerNorm (softmax over len-1 kv == 1) ----------------
__global__ __launch_bounds__(256) void k_tail(const float* __restrict__ gv, const float* __restrict__ Wv,
                                              const float* __restrict__ bv, const float* __restrict__ ipw,
                                              const float* __restrict__ ipb, const float* __restrict__ outw,
                                              const float* __restrict__ outb, const float* __restrict__ lng,
                                              const float* __restrict__ lnb, float* __restrict__ eout) {
  __shared__ float sa[256], sb[256];
  __shared__ float s_mu, s_var;
  int b = blockIdx.x, t = threadIdx.x;
  if (t < 128) sa[t] = gv[b * 128 + t];
  __syncthreads();
  float val = bv[t];
  for (int k = 0; k < 128; ++k) val += sa[k] * Wv[t * 128 + k];
  sb[t] = val;
  __syncthreads();
  float vv = ipb[512 + t];
  for (int k = 0; k < 256; ++k) vv += sb[k] * ipw[(size_t)(512 + t) * 256 + k];
  sa[t] = vv;
  __syncthreads();
  float at = outb[t];
  for (int k = 0; k < 256; ++k) at += sa[k] * outw[t * 256 + k];
  sb[t] = at;
  __syncthreads();
  for (int off = 128; off > 0; off >>= 1) {
    if (t < off) sb[t] += sb[t + off];
    __syncthreads();
  }
  if (t == 0) s_mu = sb[0] * (1.0f / 256.0f);
  __syncthreads();
  float d = at - s_mu;
  sb[t] = d * d;
  __syncthreads();
  for (int off = 128; off > 0; off >>= 1) {
    if (t < off) sb[t] += sb[t + off];
    __syncthreads();
  }
  if (t == 0) s_var = sb[0] * (1.0f / 256.0f);
  __syncthreads();
  float r = 1.0f / sqrtf(s_var + 1e-5f);
  eout[(size_t)b * 256 + t] = d * r * lng[t] + lnb[t];
}

// ---------------- broadcast per-graph embedding to nodes ----------------
__global__ void k_scat_out(const float* __restrict__ eb, const int* __restrict__ batch,
                           float* __restrict__ dout) {
  int i = blockIdx.x * 256 + threadIdx.x;  // over N*64 float4s
  int n = i >> 6, q = i & 63;
  float4 v = ((const float4*)eb)[(size_t)batch[n] * 64 + q];
  ((float4*)(dout + NGRAPH * 128))[i] = v;
}

// ---------------- launch ----------------
extern "C" void kernel_launch(void* const* d_in, const int* in_sizes, int n_in,
                              void* d_out, int out_size, void* d_ws, size_t ws_size,
                              hipStream_t stream) {
  (void)in_sizes; (void)n_in; (void)out_size; (void)ws_size;
  const float* x_bb = (const float*)d_in[0];
  const float* W1l = (const float*)d_in[2];
  const float* b1l = (const float*)d_in[3];
  const float* W1r = (const float*)d_in[4];
  const float* W2l = (const float*)d_in[5];
  const float* b2l = (const float*)d_in[6];
  const float* W2r = (const float*)d_in[7];
  const float* W3l = (const float*)d_in[8];
  const float* b3l = (const float*)d_in[9];
  const float* W3r = (const float*)d_in[10];
  const float* Wv = (const float*)d_in[15];
  const float* bv = (const float*)d_in[16];
  const float* ipw = (const float*)d_in[17];
  const float* ipb = (const float*)d_in[18];
  const float* outw = (const float*)d_in[19];
  const float* outb = (const float*)d_in[20];
  const float* lng = (const float*)d_in[21];
  const float* lnb = (const float*)d_in[22];
  const int* ei = (const int*)d_in[23];
  const int* batch = (const int*)d_in[24];
  float* dout = (float*)d_out;
  char* ws = (char*)d_ws;

  constexpr size_t O_W1L = 0;
  constexpr size_t O_W1R = O_W1L + 256 * 128 * 2;
  constexpr size_t O_W2L = O_W1R + 256 * 128 * 2;
  constexpr size_t O_W2R = O_W2L + 256 * 256 * 2;
  constexpr size_t O_W3L = O_W2R + 256 * 256 * 2;
  constexpr size_t O_W3R = O_W3L + 128 * 256 * 2;
  constexpr size_t O_XB = O_W3R + 128 * 256 * 2;                       // bf16 [N,128]
  constexpr size_t O_MEAN1 = O_XB + (size_t)N_NODES * 128 * 2;        // bf16 [N,128]
  constexpr size_t O_H1 = O_MEAN1 + (size_t)N_NODES * 128 * 2;        // bf16 [N,256]
  constexpr size_t O_MEAN2 = O_H1 + (size_t)N_NODES * 256 * 2;        // bf16 [N,256]
  constexpr size_t O_H2 = O_MEAN2 + (size_t)N_NODES * 256 * 2;        // bf16 [N,256]
  constexpr size_t O_P = O_XB;                                        // reuse: bf16 [N,128]
  constexpr size_t O_AGGP = O_MEAN2;                                  // reuse: f32  [N,128]
  constexpr size_t O_H3 = O_H1;                                       // reuse: f32  [N,128]
  constexpr size_t O_GV = O_H2 + (size_t)N_NODES * 256 * 2;           // f32 [64,128]
  constexpr size_t O_E = O_GV + 64 * 128 * 4;                         // f32 [64,256]
  constexpr size_t O_CNT = O_E + 64 * 256 * 4;
  constexpr size_t O_CUR = O_CNT + (size_t)N_NODES * 4;
  constexpr size_t O_RP = O_CUR + (size_t)N_NODES * 4;
  constexpr size_t O_INVC = O_RP + (size_t)(N_NODES + 64) * 4;
  constexpr size_t O_BSUM = O_INVC + (size_t)N_NODES * 4;
  constexpr size_t O_GST = O_BSUM + 1024;
  constexpr size_t O_PERM = O_GST + 512;

  u16* w1l = (u16*)(ws + O_W1L);  u16* w1r = (u16*)(ws + O_W1R);
  u16* w2l = (u16*)(ws + O_W2L);  u16* w2r = (u16*)(ws + O_W2R);
  u16* w3l = (u16*)(ws + O_W3L);  u16* w3r = (u16*)(ws + O_W3R);
  u16* xb = (u16*)(ws + O_XB);
  u16* mean1 = (u16*)(ws + O_MEAN1);
  u16* h1 = (u16*)(ws + O_H1);
  u16* mean2 = (u16*)(ws + O_MEAN2);
  u16* h2 = (u16*)(ws + O_H2);
  u16* Pb = (u16*)(ws + O_P);
  float* aggP = (float*)(ws + O_AGGP);
  float* h3 = (float*)(ws + O_H3);
  float* gvw = (float*)(ws + O_GV);
  float* eb = (float*)(ws + O_E);
  int* cnt = (int*)(ws + O_CNT);
  int* cursor = (int*)(ws + O_CUR);
  int* rowptr = (int*)(ws + O_RP);
  float* invc = (float*)(ws + O_INVC);
  int* bsum = (int*)(ws + O_BSUM);
  int* gstart = (int*)(ws + O_GST);
  int* perm = (int*)(ws + O_PERM);

  const int NB = (N_NODES + 255) / 256;  // 157

  // CSR build
  k_zero<<<(2 * N_NODES + 255) / 256, 256, 0, stream>>>(cnt, 2 * N_NODES);  // cnt + cursor contiguous
  k_hist<<<N_EDGES / 256, 256, 0, stream>>>(ei, cnt);
  k_blocksum<<<NB, 256, 0, stream>>>(cnt, bsum, N_NODES);
  k_scan_small<<<1, 64, 0, stream>>>(bsum, NB);
  k_rowptr<<<NB, 256, 0, stream>>>(cnt, bsum, rowptr, invc, N_NODES, N_EDGES);
  k_scatter<<<N_EDGES / 256, 256, 0, stream>>>(ei, rowptr, cursor, perm);
  k_gstart<<<1, 128, 0, stream>>>(batch, gstart);

  // bf16 conversions
  k_f2b<<<(N_NODES * 128 / 4 + 255) / 256, 256, 0, stream>>>(x_bb, xb, N_NODES * 128 / 4);
  k_f2b<<<32, 256, 0, stream>>>(W1l, w1l, 256 * 128 / 4);
  k_f2b<<<32, 256, 0, stream>>>(W1r, w1r, 256 * 128 / 4);
  k_f2b<<<64, 256, 0, stream>>>(W2l, w2l, 256 * 256 / 4);
  k_f2b<<<64, 256, 0, stream>>>(W2r, w2r, 256 * 256 / 4);
  k_f2b<<<32, 256, 0, stream>>>(W3l, w3l, 128 * 256 / 4);
  k_f2b<<<32, 256, 0, stream>>>(W3r, w3r, 128 * 256 / 4);

  dim3 blk(256);
  // SAGE1
  k_agg<128, 0><<<N_NODES / 4, blk, 0, stream>>>(xb, mean1, rowptr, perm, invc, N_NODES);
  k_gemm<256, 0><<<dim3(313, 2), blk, 0, stream>>>(mean1, w1l, 128, xb, w1r, 128, b1l, nullptr, h1, N_NODES);
  // SAGE2
  k_agg<256, 0><<<N_NODES / 4, blk, 0, stream>>>(h1, mean2, rowptr, perm, invc, N_NODES);
  k_gemm<256, 0><<<dim3(313, 2), blk, 0, stream>>>(mean2, w2l, 256, h1, w2r, 256, b2l, nullptr, h2, N_NODES);
  // SAGE3 (project-first: P = h2@W3l^T, then mean-agg P, then + h2@W3r^T + b)
  k_gemm<128, 1><<<dim3(313, 1), blk, 0, stream>>>(h2, w3l, 256, nullptr, nullptr, 0, nullptr, nullptr, Pb, N_NODES);
  k_agg<128, 1><<<N_NODES / 4, blk, 0, stream>>>(Pb, aggP, rowptr, perm, invc, N_NODES);
  k_gemm<128, 2><<<dim3(313, 1), blk, 0, stream>>>(h2, w3r, 256, nullptr, nullptr, 0, b3l, aggP, h3, N_NODES);
  // pool + per-graph tail + broadcast
  k_pool<<<NGRAPH, blk, 0, stream>>>(h3, gstart, gvw, dout);
  k_tail<<<NGRAPH, blk, 0, stream>>>(gvw, Wv, bv, ipw, ipb, outw, outb, lng, lnb, eb);
  k_scat_out<<<N_NODES * 64 / 256, blk, 0, stream>>>(eb, batch, dout);
}

// Round 2
// 405.487 us; speedup vs baseline: 1.2373x; 1.2373x over previous
//
#include <hip/hip_runtime.h>

#define N_NODES 40000
#define N_EDGES 640000
#define NGRAPH 64

typedef unsigned short u16;
typedef unsigned int u32;
typedef __attribute__((ext_vector_type(4))) float floatx4;
typedef __attribute__((ext_vector_type(8))) short short8;
typedef __attribute__((ext_vector_type(8))) __bf16 bf16x8;

__device__ __forceinline__ float bf2f(u16 u) {
  u32 x = ((u32)u) << 16;
  return __builtin_bit_cast(float, x);
}
__device__ __forceinline__ u16 f2bf(float f) {
  u32 u = __builtin_bit_cast(u32, f);
  u += 0x7fffu + ((u >> 16) & 1u);   // RNE
  return (u16)(u >> 16);
}
__device__ __forceinline__ void gld16(const void* g, void* l) {
  __builtin_amdgcn_global_load_lds(
      (const __attribute__((address_space(1))) u32*)g,
      (__attribute__((address_space(3))) u32*)l, 16, 0, 0);
}

// ---------------- CSR build ----------------
__global__ void k_zero(int* p, int n) {
  int i = blockIdx.x * 256 + threadIdx.x;
  if (i < n) p[i] = 0;
}
__global__ void k_hist(const int* __restrict__ ei, int* __restrict__ cnt) {
  int e = blockIdx.x * 256 + threadIdx.x;
  int d = ei[N_EDGES + e];
  atomicAdd(&cnt[d], 1);
}
__global__ void k_blocksum(const int* __restrict__ cnt, int* __restrict__ bsum, int n) {
  __shared__ int s[256];
  int t = threadIdx.x, i = blockIdx.x * 256 + t;
  s[t] = (i < n) ? cnt[i] : 0;
  __syncthreads();
  for (int off = 128; off > 0; off >>= 1) {
    if (t < off) s[t] += s[t + off];
    __syncthreads();
  }
  if (t == 0) bsum[blockIdx.x] = s[0];
}
// single-block Hillis-Steele exclusive scan over <=256 block sums
__global__ void k_scan_small(int* bsum, int n) {
  __shared__ int s[256];
  int t = threadIdx.x;
  int orig = (t < n) ? bsum[t] : 0;
  s[t] = orig;
  __syncthreads();
  for (int off = 1; off < 256; off <<= 1) {
    int v = (t >= off) ? s[t - off] : 0;
    __syncthreads();
    s[t] += v;
    __syncthreads();
  }
  if (t < n) bsum[t] = s[t] - orig;  // exclusive
}
__global__ void k_rowptr(const int* __restrict__ cnt, const int* __restrict__ bsum,
                         int* __restrict__ rowptr, float* __restrict__ invc, int n, int total) {
  __shared__ int s[256];
  int t = threadIdx.x, i = blockIdx.x * 256 + t;
  int c = (i < n) ? cnt[i] : 0;
  s[t] = c;
  __syncthreads();
  for (int off = 1; off < 256; off <<= 1) {
    int v = (t >= off) ? s[t - off] : 0;
    __syncthreads();
    s[t] += v;
    __syncthreads();
  }
  if (i < n) {
    rowptr[i] = bsum[blockIdx.x] + s[t] - c;   // exclusive
    invc[i] = 1.0f / (float)(c > 1 ? c : 1);
  }
  if (i == 0) rowptr[n] = total;
}
__global__ void k_scatter(const int* __restrict__ ei, const int* __restrict__ rowptr,
                          int* __restrict__ cursor, int* __restrict__ perm) {
  int e = blockIdx.x * 256 + threadIdx.x;
  int d = ei[N_EDGES + e];
  int srcn = ei[e];
  int pos = rowptr[d] + atomicAdd(&cursor[d], 1);
  perm[pos] = srcn;
}
__global__ void k_gstart(const int* __restrict__ batch, int* __restrict__ gstart) {
  int t = threadIdx.x;
  if (t <= NGRAPH) {
    int lo = 0, hi = N_NODES;
    while (lo < hi) { int mid = (lo + hi) >> 1; if (batch[mid] < t) lo = mid + 1; else hi = mid; }
    gstart[t] = lo;
  }
}

// ---------------- f32 -> bf16 convert ----------------
__global__ void k_f2b(const float* __restrict__ in, u16* __restrict__ out, int n4) {
  int i = blockIdx.x * 256 + threadIdx.x;
  if (i < n4) {
    float4 v = ((const float4*)in)[i];
    u32 lo = (u32)f2bf(v.x) | ((u32)f2bf(v.y) << 16);
    u32 hi = (u32)f2bf(v.z) | ((u32)f2bf(v.w) << 16);
    ((uint2*)out)[i] = make_uint2(lo, hi);
  }
}
// all six weight matrices in one launch (65536 float4s total)
__global__ void k_f2b6(const float* __restrict__ s0, u16* __restrict__ d0,
                       const float* __restrict__ s1, u16* __restrict__ d1,
                       const float* __restrict__ s2, u16* __restrict__ d2,
                       const float* __restrict__ s3, u16* __restrict__ d3,
                       const float* __restrict__ s4, u16* __restrict__ d4,
                       const float* __restrict__ s5, u16* __restrict__ d5) {
  int i = blockIdx.x * 256 + threadIdx.x;
  const float* s; u16* d; int off;
  if (i < 8192)       { s = s0; d = d0; off = i; }
  else if (i < 16384) { s = s1; d = d1; off = i - 8192; }
  else if (i < 32768) { s = s2; d = d2; off = i - 16384; }
  else if (i < 49152) { s = s3; d = d3; off = i - 32768; }
  else if (i < 57344) { s = s4; d = d4; off = i - 49152; }
  else                { s = s5; d = d5; off = i - 57344; }
  float4 v = ((const float4*)s)[off];
  u32 lo = (u32)f2bf(v.x) | ((u32)f2bf(v.y) << 16);
  u32 hi = (u32)f2bf(v.z) | ((u32)f2bf(v.w) << 16);
  ((uint2*)(d))[off] = make_uint2(lo, hi);
}

// ---------------- CSR mean aggregation ----------------
template <int D, int F32OUT>
__global__ __launch_bounds__(256) void k_agg(const u16* __restrict__ x, void* __restrict__ outp,
                                             const int* __restrict__ rowptr,
                                             const int* __restrict__ perm,
                                             const float* __restrict__ invc, int nn) {
  int wv = threadIdx.x >> 6, lane = threadIdx.x & 63;
  int node = blockIdx.x * 4 + wv;
  if (node >= nn) return;
  int s = rowptr[node], e = rowptr[node + 1];
  constexpr int CP = D / 64;
  float acc[CP];
#pragma unroll
  for (int i = 0; i < CP; ++i) acc[i] = 0.f;
  for (int p = s; p < e; ++p) {
    int src = perm[p];
    const u16* rp = x + (size_t)src * D + lane * CP;
    if (CP == 2) {
      u32 v = *(const u32*)rp;
      acc[0] += bf2f((u16)(v & 0xffff));
      acc[1] += bf2f((u16)(v >> 16));
    } else {
      uint2 v = *(const uint2*)rp;
      acc[0] += bf2f((u16)(v.x & 0xffff));
      acc[1] += bf2f((u16)(v.x >> 16));
      acc[2] += bf2f((u16)(v.y & 0xffff));
      acc[3] += bf2f((u16)(v.y >> 16));
    }
  }
  float iv = invc[node];
  if (F32OUT) {
    float* o = (float*)outp + (size_t)node * D + lane * CP;
    if (CP == 2) {
      ((float2*)o)[0] = make_float2(acc[0] * iv, acc[1] * iv);
    } else {
      ((float4*)o)[0] = make_float4(acc[0] * iv, acc[1] * iv, acc[2] * iv, acc[3] * iv);
    }
  } else {
    u16* o = (u16*)outp + (size_t)node * D + lane * CP;
    if (CP == 2) {
      u32 v = (u32)f2bf(acc[0] * iv) | ((u32)f2bf(acc[1] * iv) << 16);
      *(u32*)o = v;
    } else {
      u32 a = (u32)f2bf(acc[0] * iv) | ((u32)f2bf(acc[1] * iv) << 16);
      u32 b = (u32)f2bf(acc[2] * iv) | ((u32)f2bf(acc[3] * iv) << 16);
      *(uint2*)o = make_uint2(a, b);
    }
  }
}

// ---------------- bf16 MFMA GEMM:  out = epilogue(A1@W1^T + A2@W2^T) ----------------
template <int OUTW, int EPI>
__global__ __launch_bounds__(256) void k_gemm(const u16* __restrict__ A1, const u16* __restrict__ W1, int K1,
                                              const u16* __restrict__ A2, const u16* __restrict__ W2, int K2,
                                              const float* __restrict__ bias,
                                              const float* __restrict__ aggadd,
                                              void* __restrict__ outp, int M) {
  __shared__ u16 lsA[128 * 64];
  __shared__ u16 lsB[128 * 64];
  const int tid = threadIdx.x, lane = tid & 63, wv = tid >> 6;
  const int wm = wv >> 1, wn = wv & 1;
  const int row0 = blockIdx.x * 128, col0 = blockIdx.y * 128;

  floatx4 acc[4][4];
#pragma unroll
  for (int r = 0; r < 4; ++r)
#pragma unroll
    for (int c = 0; c < 4; ++c) acc[r][c] = 0.f;

  for (int seg = 0; seg < 2; ++seg) {
    const u16* A = seg ? A2 : A1;
    const u16* Wm = seg ? W2 : W1;
    const int K = seg ? K2 : K1;
    if (K == 0) continue;
    for (int k0 = 0; k0 < K; k0 += 64) {
      __syncthreads();
#pragma unroll
      for (int i = 0; i < 4; ++i) {
        int chunk = i * 256 + tid;
        int r = chunk >> 3;
        int kc = chunk & 7;
        int kcs = kc ^ (r & 7);        // pre-swizzle SOURCE, linear LDS dest
        int grow = row0 + r;
        grow = grow < M ? grow : M - 1;
        gld16(A + (size_t)grow * K + (k0 + kcs * 8), lsA + (size_t)(i * 256 + wv * 64) * 8);
        int wr = col0 + r;
        gld16(Wm + (size_t)wr * K + (k0 + kcs * 8), lsB + (size_t)(i * 256 + wv * 64) * 8);
      }
      __syncthreads();
#pragma unroll
      for (int kk = 0; kk < 2; ++kk) {
        bf16x8 af[4], bb[4];
        int kc = kk * 4 + (lane >> 4);
#pragma unroll
        for (int r = 0; r < 4; ++r) {
          int row = wm * 64 + r * 16 + (lane & 15);
          af[r] = __builtin_bit_cast(bf16x8, *(const short8*)(lsA + row * 64 + ((kc ^ (row & 7)) << 3)));
        }
#pragma unroll
        for (int c = 0; c < 4; ++c) {
          int row = wn * 64 + c * 16 + (lane & 15);
          bb[c] = __builtin_bit_cast(bf16x8, *(const short8*)(lsB + row * 64 + ((kc ^ (row & 7)) << 3)));
        }
#pragma unroll
        for (int r = 0; r < 4; ++r)
#pragma unroll
          for (int c = 0; c < 4; ++c)
            acc[r][c] = __builtin_amdgcn_mfma_f32_16x16x32_bf16(af[r], bb[c], acc[r][c], 0, 0, 0);
      }
    }
  }

  u16* ob = (u16*)outp;
  float* of = (float*)outp;
#pragma unroll
  for (int r = 0; r < 4; ++r) {
    int rowb = row0 + wm * 64 + r * 16 + ((lane >> 4) << 2);
#pragma unroll
    for (int c = 0; c < 4; ++c) {
      int col = col0 + wn * 64 + c * 16 + (lane & 15);
#pragma unroll
      for (int j = 0; j < 4; ++j) {
        int gr = rowb + j;
        if (gr < M) {
          float v = acc[r][c][j];
          if (EPI == 0) {
            v += bias[col];
            v = v > 0.f ? v : 0.f;
            ob[(size_t)gr * OUTW + col] = f2bf(v);
          } else if (EPI == 1) {
            ob[(size_t)gr * OUTW + col] = f2bf(v);
          } else {
            v += bias[col] + aggadd[(size_t)gr * OUTW + col];
            of[(size_t)gr * OUTW + col] = v;
          }
        }
      }
    }
  }
}

// ---------------- global mean pool, phase 1: run-length partial sums ----------------
// 625 blocks x 64 nodes; batch sorted -> per-thread run-accumulate, atomic flush on change
__global__ __launch_bounds__(256) void k_pool_part(const float* __restrict__ h3,
                                                   const int* __restrict__ batch,
                                                   float* __restrict__ gsum) {
  __shared__ int sb[64];
  int t = threadIdx.x;
  int n0 = blockIdx.x * 64;
  if (t < 64) sb[t] = batch[n0 + t];
  __syncthreads();
  int col = t & 127, sub = t >> 7;
  float acc = 0.f;
  int curg = -1;
  for (int i = sub; i < 64; i += 2) {
    int g = sb[i];
    if (g != curg) {
      if (curg >= 0) atomicAdd(&gsum[curg * 128 + col], acc);
      curg = g;
      acc = 0.f;
    }
    acc += h3[(size_t)(n0 + i) * 128 + col];
  }
  if (curg >= 0) atomicAdd(&gsum[curg * 128 + col], acc);
}

// ---------------- per-graph tail: mean finalize + v-proj chain + LayerNorm ----------------
__global__ __launch_bounds__(256) void k_tail(const float* __restrict__ gsum, const int* __restrict__ gstart,
                                              const float* __restrict__ Wv,
                                              const float* __restrict__ bv, const float* __restrict__ ipw,
                                              const float* __restrict__ ipb, const float* __restrict__ outw,
                                              const float* __restrict__ outb, const float* __restrict__ lng,
                                              const float* __restrict__ lnb, float* __restrict__ dout,
                                              float* __restrict__ eout) {
  __shared__ float sa[256], sb[256];
  __shared__ float s_mu, s_var;
  int b = blockIdx.x, t = threadIdx.x;
  if (t < 128) {
    int cg = gstart[b + 1] - gstart[b];
    float mean = gsum[b * 128 + t] / (float)(cg > 1 ? cg : 1);
    sa[t] = mean;
    dout[b * 128 + t] = mean;   // output 0: graph_vec
  }
  __syncthreads();
  float val = bv[t];
  for (int k = 0; k < 128; ++k) val += sa[k] * Wv[t * 128 + k];
  sb[t] = val;
  __syncthreads();
  float vv = ipb[512 + t];
  for (int k = 0; k < 256; ++k) vv += sb[k] * ipw[(size_t)(512 + t) * 256 + k];
  sa[t] = vv;
  __syncthreads();
  float at = outb[t];
  for (int k = 0; k < 256; ++k) at += sa[k] * outw[t * 256 + k];
  sb[t] = at;
  __syncthreads();
  for (int off = 128; off > 0; off >>= 1) {
    if (t < off) sb[t] += sb[t + off];
    __syncthreads();
  }
  if (t == 0) s_mu = sb[0] * (1.0f / 256.0f);
  __syncthreads();
  float d = at - s_mu;
  sb[t] = d * d;
  __syncthreads();
  for (int off = 128; off > 0; off >>= 1) {
    if (t < off) sb[t] += sb[t + off];
    __syncthreads();
  }
  if (t == 0) s_var = sb[0] * (1.0f / 256.0f);
  __syncthreads();
  float r = 1.0f / sqrtf(s_var + 1e-5f);
  eout[(size_t)b * 256 + t] = d * r * lng[t] + lnb[t];
}

// ---------------- broadcast per-graph embedding to nodes ----------------
__global__ void k_scat_out(const float* __restrict__ eb, const int* __restrict__ batch,
                           float* __restrict__ dout) {
  int i = blockIdx.x * 256 + threadIdx.x;
  int n = i >> 6, q = i & 63;
  float4 v = ((const float4*)eb)[(size_t)batch[n] * 64 + q];
  ((float4*)(dout + NGRAPH * 128))[i] = v;
}

// ---------------- launch ----------------
extern "C" void kernel_launch(void* const* d_in, const int* in_sizes, int n_in,
                              void* d_out, int out_size, void* d_ws, size_t ws_size,
                              hipStream_t stream) {
  (void)in_sizes; (void)n_in; (void)out_size; (void)ws_size;
  const float* x_bb = (const float*)d_in[0];
  const float* W1l = (const float*)d_in[2];
  const float* b1l = (const float*)d_in[3];
  const float* W1r = (const float*)d_in[4];
  const float* W2l = (const float*)d_in[5];
  const float* b2l = (const float*)d_in[6];
  const float* W2r = (const float*)d_in[7];
  const float* W3l = (const float*)d_in[8];
  const float* b3l = (const float*)d_in[9];
  const float* W3r = (const float*)d_in[10];
  const float* Wv = (const float*)d_in[15];
  const float* bv = (const float*)d_in[16];
  const float* ipw = (const float*)d_in[17];
  const float* ipb = (const float*)d_in[18];
  const float* outw = (const float*)d_in[19];
  const float* outb = (const float*)d_in[20];
  const float* lng = (const float*)d_in[21];
  const float* lnb = (const float*)d_in[22];
  const int* ei = (const int*)d_in[23];
  const int* batch = (const int*)d_in[24];
  float* dout = (float*)d_out;
  char* ws = (char*)d_ws;

  constexpr size_t O_W1L = 0;
  constexpr size_t O_W1R = O_W1L + 256 * 128 * 2;
  constexpr size_t O_W2L = O_W1R + 256 * 128 * 2;
  constexpr size_t O_W2R = O_W2L + 256 * 256 * 2;
  constexpr size_t O_W3L = O_W2R + 256 * 256 * 2;
  constexpr size_t O_W3R = O_W3L + 128 * 256 * 2;
  constexpr size_t O_XB = O_W3R + 128 * 256 * 2;                      // bf16 [N,128]
  constexpr size_t O_MEAN1 = O_XB + (size_t)N_NODES * 128 * 2;       // bf16 [N,128]
  constexpr size_t O_H1 = O_MEAN1 + (size_t)N_NODES * 128 * 2;       // bf16 [N,256]
  constexpr size_t O_MEAN2 = O_H1 + (size_t)N_NODES * 256 * 2;       // bf16 [N,256]
  constexpr size_t O_H2 = O_MEAN2 + (size_t)N_NODES * 256 * 2;       // bf16 [N,256]
  constexpr size_t O_P = O_XB;                                       // reuse: bf16 [N,128]
  constexpr size_t O_AGGP = O_MEAN2;                                 // reuse: f32  [N,128]
  constexpr size_t O_H3 = O_H1;                                      // reuse: f32  [N,128]
  constexpr size_t O_E = O_H2 + (size_t)N_NODES * 256 * 2;           // f32 [64,256]
  constexpr size_t O_CNT = O_E + 64 * 256 * 4;                       // cnt | cursor | gsum contiguous (zeroed together)
  constexpr size_t O_CUR = O_CNT + (size_t)N_NODES * 4;
  constexpr size_t O_GSUM = O_CUR + (size_t)N_NODES * 4;             // f32 [64,128]
  constexpr size_t O_RP = O_GSUM + 64 * 128 * 4;
  constexpr size_t O_INVC = O_RP + (size_t)(N_NODES + 64) * 4;
  constexpr size_t O_BSUM = O_INVC + (size_t)N_NODES * 4;
  constexpr size_t O_GST = O_BSUM + 1024;
  constexpr size_t O_PERM = O_GST + 512;

  u16* w1l = (u16*)(ws + O_W1L);  u16* w1r = (u16*)(ws + O_W1R);
  u16* w2l = (u16*)(ws + O_W2L);  u16* w2r = (u16*)(ws + O_W2R);
  u16* w3l = (u16*)(ws + O_W3L);  u16* w3r = (u16*)(ws + O_W3R);
  u16* xb = (u16*)(ws + O_XB);
  u16* mean1 = (u16*)(ws + O_MEAN1);
  u16* h1 = (u16*)(ws + O_H1);
  u16* mean2 = (u16*)(ws + O_MEAN2);
  u16* h2 = (u16*)(ws + O_H2);
  u16* Pb = (u16*)(ws + O_P);
  float* aggP = (float*)(ws + O_AGGP);
  float* h3 = (float*)(ws + O_H3);
  float* eb = (float*)(ws + O_E);
  int* cnt = (int*)(ws + O_CNT);
  int* cursor = (int*)(ws + O_CUR);
  float* gsum = (float*)(ws + O_GSUM);
  int* rowptr = (int*)(ws + O_RP);
  float* invc = (float*)(ws + O_INVC);
  int* bsum = (int*)(ws + O_BSUM);
  int* gstart = (int*)(ws + O_GST);
  int* perm = (int*)(ws + O_PERM);

  const int NB = (N_NODES + 255) / 256;  // 157

  // CSR build (cnt + cursor + gsum zeroed in one launch)
  k_zero<<<(2 * N_NODES + 8192 + 255) / 256, 256, 0, stream>>>(cnt, 2 * N_NODES + 8192);
  k_hist<<<N_EDGES / 256, 256, 0, stream>>>(ei, cnt);
  k_blocksum<<<NB, 256, 0, stream>>>(cnt, bsum, N_NODES);
  k_scan_small<<<1, 256, 0, stream>>>(bsum, NB);
  k_rowptr<<<NB, 256, 0, stream>>>(cnt, bsum, rowptr, invc, N_NODES, N_EDGES);
  k_scatter<<<N_EDGES / 256, 256, 0, stream>>>(ei, rowptr, cursor, perm);
  k_gstart<<<1, 128, 0, stream>>>(batch, gstart);

  // bf16 conversions
  k_f2b<<<(N_NODES * 128 / 4 + 255) / 256, 256, 0, stream>>>(x_bb, xb, N_NODES * 128 / 4);
  k_f2b6<<<256, 256, 0, stream>>>(W1l, w1l, W1r, w1r, W2l, w2l, W2r, w2r, W3l, w3l, W3r, w3r);

  dim3 blk(256);
  // SAGE1
  k_agg<128, 0><<<N_NODES / 4, blk, 0, stream>>>(xb, mean1, rowptr, perm, invc, N_NODES);
  k_gemm<256, 0><<<dim3(313, 2), blk, 0, stream>>>(mean1, w1l, 128, xb, w1r, 128, b1l, nullptr, h1, N_NODES);
  // SAGE2
  k_agg<256, 0><<<N_NODES / 4, blk, 0, stream>>>(h1, mean2, rowptr, perm, invc, N_NODES);
  k_gemm<256, 0><<<dim3(313, 2), blk, 0, stream>>>(mean2, w2l, 256, h1, w2r, 256, b2l, nullptr, h2, N_NODES);
  // SAGE3 (project-first)
  k_gemm<128, 1><<<dim3(313, 1), blk, 0, stream>>>(h2, w3l, 256, nullptr, nullptr, 0, nullptr, nullptr, Pb, N_NODES);
  k_agg<128, 1><<<N_NODES / 4, blk, 0, stream>>>(Pb, aggP, rowptr, perm, invc, N_NODES);
  k_gemm<128, 2><<<dim3(313, 1), blk, 0, stream>>>(h2, w3r, 256, nullptr, nullptr, 0, b3l, aggP, h3, N_NODES);
  // pool (partial sums) + per-graph tail + broadcast
  k_pool_part<<<N_NODES / 64, blk, 0, stream>>>(h3, batch, gsum);
  k_tail<<<NGRAPH, blk, 0, stream>>>(gsum, gstart, Wv, bv, ipw, ipb, outw, outb, lng, lnb, dout, eb);
  k_scat_out<<<N_NODES * 64 / 256, blk, 0, stream>>>(eb, batch, dout);
}

// Round 3
// 301.141 us; speedup vs baseline: 1.6660x; 1.3465x over previous
//
#include <hip/hip_runtime.h>

#define N_NODES 40000
#define N_EDGES 640000
#define NGRAPH 64

typedef unsigned short u16;
typedef unsigned int u32;
typedef __attribute__((ext_vector_type(4))) float floatx4;
typedef __attribute__((ext_vector_type(8))) short short8;
typedef __attribute__((ext_vector_type(8))) __bf16 bf16x8;

__device__ __forceinline__ float bf2f(u16 u) {
  u32 x = ((u32)u) << 16;
  return __builtin_bit_cast(float, x);
}
__device__ __forceinline__ u16 f2bf(float f) {
  u32 u = __builtin_bit_cast(u32, f);
  u += 0x7fffu + ((u >> 16) & 1u);   // RNE
  return (u16)(u >> 16);
}
__device__ __forceinline__ void gld16(const void* g, void* l) {
  __builtin_amdgcn_global_load_lds(
      (const __attribute__((address_space(1))) u32*)g,
      (__attribute__((address_space(3))) u32*)l, 16, 0, 0);
}

// ---------------- CSR build ----------------
__global__ void k_zero(int* p, int n) {
  int i = blockIdx.x * 256 + threadIdx.x;
  if (i < n) p[i] = 0;
}
__global__ void k_hist(const int* __restrict__ ei, int* __restrict__ cnt) {
  int e = blockIdx.x * 256 + threadIdx.x;
  int d = ei[N_EDGES + e];
  atomicAdd(&cnt[d], 1);
}
__global__ void k_blocksum(const int* __restrict__ cnt, int* __restrict__ bsum, int n) {
  __shared__ int s[256];
  int t = threadIdx.x, i = blockIdx.x * 256 + t;
  s[t] = (i < n) ? cnt[i] : 0;
  __syncthreads();
  for (int off = 128; off > 0; off >>= 1) {
    if (t < off) s[t] += s[t + off];
    __syncthreads();
  }
  if (t == 0) bsum[blockIdx.x] = s[0];
}
__global__ void k_scan_small(int* bsum, int n) {
  __shared__ int s[256];
  int t = threadIdx.x;
  int orig = (t < n) ? bsum[t] : 0;
  s[t] = orig;
  __syncthreads();
  for (int off = 1; off < 256; off <<= 1) {
    int v = (t >= off) ? s[t - off] : 0;
    __syncthreads();
    s[t] += v;
    __syncthreads();
  }
  if (t < n) bsum[t] = s[t] - orig;  // exclusive
}
__global__ void k_rowptr(const int* __restrict__ cnt, const int* __restrict__ bsum,
                         int* __restrict__ rowptr, float* __restrict__ invc, int n, int total) {
  __shared__ int s[256];
  int t = threadIdx.x, i = blockIdx.x * 256 + t;
  int c = (i < n) ? cnt[i] : 0;
  s[t] = c;
  __syncthreads();
  for (int off = 1; off < 256; off <<= 1) {
    int v = (t >= off) ? s[t - off] : 0;
    __syncthreads();
    s[t] += v;
    __syncthreads();
  }
  if (i < n) {
    rowptr[i] = bsum[blockIdx.x] + s[t] - c;   // exclusive
    invc[i] = 1.0f / (float)(c > 1 ? c : 1);
  }
  if (i == 0) rowptr[n] = total;
}
__global__ void k_scatter(const int* __restrict__ ei, const int* __restrict__ rowptr,
                          int* __restrict__ cursor, int* __restrict__ perm) {
  int e = blockIdx.x * 256 + threadIdx.x;
  int d = ei[N_EDGES + e];
  int srcn = ei[e];
  int pos = rowptr[d] + atomicAdd(&cursor[d], 1);
  perm[pos] = srcn;
}
__global__ void k_gstart(const int* __restrict__ batch, int* __restrict__ gstart) {
  int t = threadIdx.x;
  if (t <= NGRAPH) {
    int lo = 0, hi = N_NODES;
    while (lo < hi) { int mid = (lo + hi) >> 1; if (batch[mid] < t) lo = mid + 1; else hi = mid; }
    gstart[t] = lo;
  }
}

// ---------------- f32 -> bf16 convert ----------------
__global__ void k_f2b(const float* __restrict__ in, u16* __restrict__ out, int n4) {
  int i = blockIdx.x * 256 + threadIdx.x;
  if (i < n4) {
    float4 v = ((const float4*)in)[i];
    u32 lo = (u32)f2bf(v.x) | ((u32)f2bf(v.y) << 16);
    u32 hi = (u32)f2bf(v.z) | ((u32)f2bf(v.w) << 16);
    ((uint2*)out)[i] = make_uint2(lo, hi);
  }
}
__global__ void k_f2b6(const float* __restrict__ s0, u16* __restrict__ d0,
                       const float* __restrict__ s1, u16* __restrict__ d1,
                       const float* __restrict__ s2, u16* __restrict__ d2,
                       const float* __restrict__ s3, u16* __restrict__ d3,
                       const float* __restrict__ s4, u16* __restrict__ d4,
                       const float* __restrict__ s5, u16* __restrict__ d5) {
  int i = blockIdx.x * 256 + threadIdx.x;
  const float* s; u16* d; int off;
  if (i < 8192)       { s = s0; d = d0; off = i; }
  else if (i < 16384) { s = s1; d = d1; off = i - 8192; }
  else if (i < 32768) { s = s2; d = d2; off = i - 16384; }
  else if (i < 49152) { s = s3; d = d3; off = i - 32768; }
  else if (i < 57344) { s = s4; d = d4; off = i - 49152; }
  else                { s = s5; d = d5; off = i - 57344; }
  float4 v = ((const float4*)s)[off];
  u32 lo = (u32)f2bf(v.x) | ((u32)f2bf(v.y) << 16);
  u32 hi = (u32)f2bf(v.z) | ((u32)f2bf(v.w) << 16);
  ((uint2*)(d))[off] = make_uint2(lo, hi);
}

// ---------------- CSR mean aggregation (4 edge-slots x 16 lanes, pair-unrolled) ----------------
// one wave per dst node; 8 edges in flight per wave; cross-slot shfl_xor reduce
template <int D, int F32OUT>
__global__ __launch_bounds__(256) void k_agg(const u16* __restrict__ x, void* __restrict__ outp,
                                             const int* __restrict__ rowptr,
                                             const int* __restrict__ perm,
                                             const float* __restrict__ invc, int nn) {
  int wv = threadIdx.x >> 6, lane = threadIdx.x & 63;
  int node = blockIdx.x * 4 + wv;
  if (node >= nn) return;
  int s = rowptr[node], e = rowptr[node + 1];
  int slot = lane >> 4, lsub = lane & 15;
  constexpr int FR = D / 16;  // f32 acc per lane: 8 (D=128) or 16 (D=256)
  float acc[FR];
#pragma unroll
  for (int i = 0; i < FR; ++i) acc[i] = 0.f;

  int p = s + slot;
  // pair-unrolled: 8 edges in flight across the wave
  for (; p + 4 < e; p += 8) {
    int src0 = perm[p];
    int src1 = perm[p + 4];
    const u16* rp0 = x + (size_t)src0 * D + lsub * FR;
    const u16* rp1 = x + (size_t)src1 * D + lsub * FR;
    if (D == 128) {
      uint4 a = *(const uint4*)rp0;
      uint4 b = *(const uint4*)rp1;
      u32 va[4] = {a.x, a.y, a.z, a.w}, vb[4] = {b.x, b.y, b.z, b.w};
#pragma unroll
      for (int j = 0; j < 4; ++j) {
        acc[2 * j] += bf2f((u16)(va[j] & 0xffff)) + bf2f((u16)(vb[j] & 0xffff));
        acc[2 * j + 1] += bf2f((u16)(va[j] >> 16)) + bf2f((u16)(vb[j] >> 16));
      }
    } else {
      uint4 a0 = *(const uint4*)rp0;
      uint4 a1 = *(const uint4*)(rp0 + 8);
      uint4 b0 = *(const uint4*)rp1;
      uint4 b1 = *(const uint4*)(rp1 + 8);
      u32 va[8] = {a0.x, a0.y, a0.z, a0.w, a1.x, a1.y, a1.z, a1.w};
      u32 vb[8] = {b0.x, b0.y, b0.z, b0.w, b1.x, b1.y, b1.z, b1.w};
#pragma unroll
      for (int j = 0; j < 8; ++j) {
        acc[2 * j] += bf2f((u16)(va[j] & 0xffff)) + bf2f((u16)(vb[j] & 0xffff));
        acc[2 * j + 1] += bf2f((u16)(va[j] >> 16)) + bf2f((u16)(vb[j] >> 16));
      }
    }
  }
  if (p < e) {
    int src = perm[p];
    const u16* rp = x + (size_t)src * D + lsub * FR;
    if (D == 128) {
      uint4 a = *(const uint4*)rp;
      u32 va[4] = {a.x, a.y, a.z, a.w};
#pragma unroll
      for (int j = 0; j < 4; ++j) {
        acc[2 * j] += bf2f((u16)(va[j] & 0xffff));
        acc[2 * j + 1] += bf2f((u16)(va[j] >> 16));
      }
    } else {
      uint4 a0 = *(const uint4*)rp;
      uint4 a1 = *(const uint4*)(rp + 8);
      u32 va[8] = {a0.x, a0.y, a0.z, a0.w, a1.x, a1.y, a1.z, a1.w};
#pragma unroll
      for (int j = 0; j < 8; ++j) {
        acc[2 * j] += bf2f((u16)(va[j] & 0xffff));
        acc[2 * j + 1] += bf2f((u16)(va[j] >> 16));
      }
    }
  }

  // reduce across the 4 slots (lane bits 4,5)
#pragma unroll
  for (int i = 0; i < FR; ++i) {
    acc[i] += __shfl_xor(acc[i], 16, 64);
    acc[i] += __shfl_xor(acc[i], 32, 64);
  }

  float iv = invc[node];
  if (slot == 0) {  // lanes 0..15 write the full row
    if (F32OUT) {
      float* o = (float*)outp + (size_t)node * D + lsub * FR;
#pragma unroll
      for (int i = 0; i < FR; i += 4)
        ((float4*)(o + i))[0] = make_float4(acc[i] * iv, acc[i + 1] * iv, acc[i + 2] * iv, acc[i + 3] * iv);
    } else {
      u16* o = (u16*)outp + (size_t)node * D + lsub * FR;
      u32 w[FR / 2];
#pragma unroll
      for (int i = 0; i < FR / 2; ++i)
        w[i] = (u32)f2bf(acc[2 * i] * iv) | ((u32)f2bf(acc[2 * i + 1] * iv) << 16);
#pragma unroll
      for (int i = 0; i < FR / 2; i += 4)
        ((uint4*)((u32*)o + i))[0] = make_uint4(w[i], w[i + 1], w[i + 2], w[i + 3]);
    }
  }
}

// ---------------- bf16 MFMA GEMM:  out = epilogue(A1@W1^T + A2@W2^T) ----------------
template <int OUTW, int EPI>
__global__ __launch_bounds__(256) void k_gemm(const u16* __restrict__ A1, const u16* __restrict__ W1, int K1,
                                              const u16* __restrict__ A2, const u16* __restrict__ W2, int K2,
                                              const float* __restrict__ bias,
                                              const float* __restrict__ aggadd,
                                              void* __restrict__ outp, int M) {
  __shared__ u16 lsA[128 * 64];
  __shared__ u16 lsB[128 * 64];
  const int tid = threadIdx.x, lane = tid & 63, wv = tid >> 6;
  const int wm = wv >> 1, wn = wv & 1;
  const int row0 = blockIdx.x * 128, col0 = blockIdx.y * 128;

  floatx4 acc[4][4];
#pragma unroll
  for (int r = 0; r < 4; ++r)
#pragma unroll
    for (int c = 0; c < 4; ++c) acc[r][c] = 0.f;

  for (int seg = 0; seg < 2; ++seg) {
    const u16* A = seg ? A2 : A1;
    const u16* Wm = seg ? W2 : W1;
    const int K = seg ? K2 : K1;
    if (K == 0) continue;
    for (int k0 = 0; k0 < K; k0 += 64) {
      __syncthreads();
#pragma unroll
      for (int i = 0; i < 4; ++i) {
        int chunk = i * 256 + tid;
        int r = chunk >> 3;
        int kc = chunk & 7;
        int kcs = kc ^ (r & 7);        // pre-swizzle SOURCE, linear LDS dest
        int grow = row0 + r;
        grow = grow < M ? grow : M - 1;
        gld16(A + (size_t)grow * K + (k0 + kcs * 8), lsA + (size_t)(i * 256 + wv * 64) * 8);
        int wr = col0 + r;
        gld16(Wm + (size_t)wr * K + (k0 + kcs * 8), lsB + (size_t)(i * 256 + wv * 64) * 8);
      }
      __syncthreads();
#pragma unroll
      for (int kk = 0; kk < 2; ++kk) {
        bf16x8 af[4], bb[4];
        int kc = kk * 4 + (lane >> 4);
#pragma unroll
        for (int r = 0; r < 4; ++r) {
          int row = wm * 64 + r * 16 + (lane & 15);
          af[r] = __builtin_bit_cast(bf16x8, *(const short8*)(lsA + row * 64 + ((kc ^ (row & 7)) << 3)));
        }
#pragma unroll
        for (int c = 0; c < 4; ++c) {
          int row = wn * 64 + c * 16 + (lane & 15);
          bb[c] = __builtin_bit_cast(bf16x8, *(const short8*)(lsB + row * 64 + ((kc ^ (row & 7)) << 3)));
        }
#pragma unroll
        for (int r = 0; r < 4; ++r)
#pragma unroll
          for (int c = 0; c < 4; ++c)
            acc[r][c] = __builtin_amdgcn_mfma_f32_16x16x32_bf16(af[r], bb[c], acc[r][c], 0, 0, 0);
      }
    }
  }

  u16* ob = (u16*)outp;
  float* of = (float*)outp;
#pragma unroll
  for (int r = 0; r < 4; ++r) {
    int rowb = row0 + wm * 64 + r * 16 + ((lane >> 4) << 2);
#pragma unroll
    for (int c = 0; c < 4; ++c) {
      int col = col0 + wn * 64 + c * 16 + (lane & 15);
#pragma unroll
      for (int j = 0; j < 4; ++j) {
        int gr = rowb + j;
        if (gr < M) {
          float v = acc[r][c][j];
          if (EPI == 0) {
            v += bias[col];
            v = v > 0.f ? v : 0.f;
            ob[(size_t)gr * OUTW + col] = f2bf(v);
          } else if (EPI == 1) {
            ob[(size_t)gr * OUTW + col] = f2bf(v);
          } else {
            v += bias[col] + aggadd[(size_t)gr * OUTW + col];
            of[(size_t)gr * OUTW + col] = v;
          }
        }
      }
    }
  }
}

// ---------------- global mean pool, phase 1: run-length partial sums ----------------
__global__ __launch_bounds__(256) void k_pool_part(const float* __restrict__ h3,
                                                   const int* __restrict__ batch,
                                                   float* __restrict__ gsum) {
  __shared__ int sb[64];
  int t = threadIdx.x;
  int n0 = blockIdx.x * 64;
  if (t < 64) sb[t] = batch[n0 + t];
  __syncthreads();
  int col = t & 127, sub = t >> 7;
  float acc = 0.f;
  int curg = -1;
  for (int i = sub; i < 64; i += 2) {
    int g = sb[i];
    if (g != curg) {
      if (curg >= 0) atomicAdd(&gsum[curg * 128 + col], acc);
      curg = g;
      acc = 0.f;
    }
    acc += h3[(size_t)(n0 + i) * 128 + col];
  }
  if (curg >= 0) atomicAdd(&gsum[curg * 128 + col], acc);
}

// ---------------- per-graph tail: mean finalize + v-proj chain + LayerNorm ----------------
__global__ __launch_bounds__(256) void k_tail(const float* __restrict__ gsum, const int* __restrict__ gstart,
                                              const float* __restrict__ Wv,
                                              const float* __restrict__ bv, const float* __restrict__ ipw,
                                              const float* __restrict__ ipb, const float* __restrict__ outw,
                                              const float* __restrict__ outb, const float* __restrict__ lng,
                                              const float* __restrict__ lnb, float* __restrict__ dout,
                                              float* __restrict__ eout) {
  __shared__ float sa[256], sb[256];
  __shared__ float s_mu, s_var;
  int b = blockIdx.x, t = threadIdx.x;
  if (t < 128) {
    int cg = gstart[b + 1] - gstart[b];
    float mean = gsum[b * 128 + t] / (float)(cg > 1 ? cg : 1);
    sa[t] = mean;
    dout[b * 128 + t] = mean;   // output 0: graph_vec
  }
  __syncthreads();
  float val = bv[t];
  for (int k = 0; k < 128; ++k) val += sa[k] * Wv[t * 128 + k];
  sb[t] = val;
  __syncthreads();
  float vv = ipb[512 + t];
  for (int k = 0; k < 256; ++k) vv += sb[k] * ipw[(size_t)(512 + t) * 256 + k];
  sa[t] = vv;
  __syncthreads();
  float at = outb[t];
  for (int k = 0; k < 256; ++k) at += sa[k] * outw[t * 256 + k];
  sb[t] = at;
  __syncthreads();
  for (int off = 128; off > 0; off >>= 1) {
    if (t < off) sb[t] += sb[t + off];
    __syncthreads();
  }
  if (t == 0) s_mu = sb[0] * (1.0f / 256.0f);
  __syncthreads();
  float d = at - s_mu;
  sb[t] = d * d;
  __syncthreads();
  for (int off = 128; off > 0; off >>= 1) {
    if (t < off) sb[t] += sb[t + off];
    __syncthreads();
  }
  if (t == 0) s_var = sb[0] * (1.0f / 256.0f);
  __syncthreads();
  float r = 1.0f / sqrtf(s_var + 1e-5f);
  eout[(size_t)b * 256 + t] = d * r * lng[t] + lnb[t];
}

// ---------------- broadcast per-graph embedding to nodes ----------------
__global__ void k_scat_out(const float* __restrict__ eb, const int* __restrict__ batch,
                           float* __restrict__ dout) {
  int i = blockIdx.x * 256 + threadIdx.x;
  int n = i >> 6, q = i & 63;
  float4 v = ((const float4*)eb)[(size_t)batch[n] * 64 + q];
  ((float4*)(dout + NGRAPH * 128))[i] = v;
}

// ---------------- launch ----------------
extern "C" void kernel_launch(void* const* d_in, const int* in_sizes, int n_in,
                              void* d_out, int out_size, void* d_ws, size_t ws_size,
                              hipStream_t stream) {
  (void)in_sizes; (void)n_in; (void)out_size; (void)ws_size;
  const float* x_bb = (const float*)d_in[0];
  const float* W1l = (const float*)d_in[2];
  const float* b1l = (const float*)d_in[3];
  const float* W1r = (const float*)d_in[4];
  const float* W2l = (const float*)d_in[5];
  const float* b2l = (const float*)d_in[6];
  const float* W2r = (const float*)d_in[7];
  const float* W3l = (const float*)d_in[8];
  const float* b3l = (const float*)d_in[9];
  const float* W3r = (const float*)d_in[10];
  const float* Wv = (const float*)d_in[15];
  const float* bv = (const float*)d_in[16];
  const float* ipw = (const float*)d_in[17];
  const float* ipb = (const float*)d_in[18];
  const float* outw = (const float*)d_in[19];
  const float* outb = (const float*)d_in[20];
  const float* lng = (const float*)d_in[21];
  const float* lnb = (const float*)d_in[22];
  const int* ei = (const int*)d_in[23];
  const int* batch = (const int*)d_in[24];
  float* dout = (float*)d_out;
  char* ws = (char*)d_ws;

  constexpr size_t O_W1L = 0;
  constexpr size_t O_W1R = O_W1L + 256 * 128 * 2;
  constexpr size_t O_W2L = O_W1R + 256 * 128 * 2;
  constexpr size_t O_W2R = O_W2L + 256 * 256 * 2;
  constexpr size_t O_W3L = O_W2R + 256 * 256 * 2;
  constexpr size_t O_W3R = O_W3L + 128 * 256 * 2;
  constexpr size_t O_XB = O_W3R + 128 * 256 * 2;                      // bf16 [N,128]
  constexpr size_t O_MEAN1 = O_XB + (size_t)N_NODES * 128 * 2;       // bf16 [N,128]
  constexpr size_t O_H1 = O_MEAN1 + (size_t)N_NODES * 128 * 2;       // bf16 [N,256]
  constexpr size_t O_MEAN2 = O_H1 + (size_t)N_NODES * 256 * 2;       // bf16 [N,256]
  constexpr size_t O_H2 = O_MEAN2 + (size_t)N_NODES * 256 * 2;       // bf16 [N,256]
  constexpr size_t O_P = O_XB;                                       // reuse: bf16 [N,128]
  constexpr size_t O_AGGP = O_MEAN2;                                 // reuse: f32  [N,128]
  constexpr size_t O_H3 = O_H1;                                      // reuse: f32  [N,128]
  constexpr size_t O_E = O_H2 + (size_t)N_NODES * 256 * 2;           // f32 [64,256]
  constexpr size_t O_CNT = O_E + 64 * 256 * 4;                       // cnt | cursor | gsum contiguous
  constexpr size_t O_CUR = O_CNT + (size_t)N_NODES * 4;
  constexpr size_t O_GSUM = O_CUR + (size_t)N_NODES * 4;             // f32 [64,128]
  constexpr size_t O_RP = O_GSUM + 64 * 128 * 4;
  constexpr size_t O_INVC = O_RP + (size_t)(N_NODES + 64) * 4;
  constexpr size_t O_BSUM = O_INVC + (size_t)N_NODES * 4;
  constexpr size_t O_GST = O_BSUM + 1024;
  constexpr size_t O_PERM = O_GST + 512;

  u16* w1l = (u16*)(ws + O_W1L);  u16* w1r = (u16*)(ws + O_W1R);
  u16* w2l = (u16*)(ws + O_W2L);  u16* w2r = (u16*)(ws + O_W2R);
  u16* w3l = (u16*)(ws + O_W3L);  u16* w3r = (u16*)(ws + O_W3R);
  u16* xb = (u16*)(ws + O_XB);
  u16* mean1 = (u16*)(ws + O_MEAN1);
  u16* h1 = (u16*)(ws + O_H1);
  u16* mean2 = (u16*)(ws + O_MEAN2);
  u16* h2 = (u16*)(ws + O_H2);
  u16* Pb = (u16*)(ws + O_P);
  float* aggP = (float*)(ws + O_AGGP);
  float* h3 = (float*)(ws + O_H3);
  float* eb = (float*)(ws + O_E);
  int* cnt = (int*)(ws + O_CNT);
  int* cursor = (int*)(ws + O_CUR);
  float* gsum = (float*)(ws + O_GSUM);
  int* rowptr = (int*)(ws + O_RP);
  float* invc = (float*)(ws + O_INVC);
  int* bsum = (int*)(ws + O_BSUM);
  int* gstart = (int*)(ws + O_GST);
  int* perm = (int*)(ws + O_PERM);

  const int NB = (N_NODES + 255) / 256;  // 157

  // CSR build (cnt + cursor + gsum zeroed in one launch)
  k_zero<<<(2 * N_NODES + 8192 + 255) / 256, 256, 0, stream>>>(cnt, 2 * N_NODES + 8192);
  k_hist<<<N_EDGES / 256, 256, 0, stream>>>(ei, cnt);
  k_blocksum<<<NB, 256, 0, stream>>>(cnt, bsum, N_NODES);
  k_scan_small<<<1, 256, 0, stream>>>(bsum, NB);
  k_rowptr<<<NB, 256, 0, stream>>>(cnt, bsum, rowptr, invc, N_NODES, N_EDGES);
  k_scatter<<<N_EDGES / 256, 256, 0, stream>>>(ei, rowptr, cursor, perm);
  k_gstart<<<1, 128, 0, stream>>>(batch, gstart);

  // bf16 conversions
  k_f2b<<<(N_NODES * 128 / 4 + 255) / 256, 256, 0, stream>>>(x_bb, xb, N_NODES * 128 / 4);
  k_f2b6<<<256, 256, 0, stream>>>(W1l, w1l, W1r, w1r, W2l, w2l, W2r, w2r, W3l, w3l, W3r, w3r);

  dim3 blk(256);
  // SAGE1
  k_agg<128, 0><<<N_NODES / 4, blk, 0, stream>>>(xb, mean1, rowptr, perm, invc, N_NODES);
  k_gemm<256, 0><<<dim3(313, 2), blk, 0, stream>>>(mean1, w1l, 128, xb, w1r, 128, b1l, nullptr, h1, N_NODES);
  // SAGE2
  k_agg<256, 0><<<N_NODES / 4, blk, 0, stream>>>(h1, mean2, rowptr, perm, invc, N_NODES);
  k_gemm<256, 0><<<dim3(313, 2), blk, 0, stream>>>(mean2, w2l, 256, h1, w2r, 256, b2l, nullptr, h2, N_NODES);
  // SAGE3 (project-first)
  k_gemm<128, 1><<<dim3(313, 1), blk, 0, stream>>>(h2, w3l, 256, nullptr, nullptr, 0, nullptr, nullptr, Pb, N_NODES);
  k_agg<128, 1><<<N_NODES / 4, blk, 0, stream>>>(Pb, aggP, rowptr, perm, invc, N_NODES);
  k_gemm<128, 2><<<dim3(313, 1), blk, 0, stream>>>(h2, w3r, 256, nullptr, nullptr, 0, b3l, aggP, h3, N_NODES);
  // pool (partial sums) + per-graph tail + broadcast
  k_pool_part<<<N_NODES / 64, blk, 0, stream>>>(h3, batch, gsum);
  k_tail<<<NGRAPH, blk, 0, stream>>>(gsum, gstart, Wv, bv, ipw, ipb, outw, outb, lng, lnb, dout, eb);
  k_scat_out<<<N_NODES * 64 / 256, blk, 0, stream>>>(eb, batch, dout);
}

// Round 4
// 295.669 us; speedup vs baseline: 1.6968x; 1.0185x over previous
//
#include <hip/hip_runtime.h>

#define N_NODES 40000
#define N_EDGES 640000
#define NGRAPH 64

typedef unsigned short u16;
typedef unsigned int u32;
typedef __attribute__((ext_vector_type(4))) float floatx4;
typedef __attribute__((ext_vector_type(8))) short short8;
typedef __attribute__((ext_vector_type(8))) __bf16 bf16x8;

__device__ __forceinline__ float bf2f(u16 u) {
  u32 x = ((u32)u) << 16;
  return __builtin_bit_cast(float, x);
}
__device__ __forceinline__ u16 f2bf(float f) {
  u32 u = __builtin_bit_cast(u32, f);
  u += 0x7fffu + ((u >> 16) & 1u);   // RNE
  return (u16)(u >> 16);
}
__device__ __forceinline__ void gld16(const void* g, void* l) {
  __builtin_amdgcn_global_load_lds(
      (const __attribute__((address_space(1))) u32*)g,
      (__attribute__((address_space(3))) u32*)l, 16, 0, 0);
}

// ---------------- CSR build ----------------
__global__ void k_zero(int* p, int n) {
  int i = blockIdx.x * 256 + threadIdx.x;
  if (i < n) p[i] = 0;
}
__global__ void k_hist(const int* __restrict__ ei, int* __restrict__ cnt) {
  int e = blockIdx.x * 256 + threadIdx.x;
  int d = ei[N_EDGES + e];
  atomicAdd(&cnt[d], 1);
}
__global__ void k_blocksum(const int* __restrict__ cnt, int* __restrict__ bsum, int n) {
  __shared__ int s[256];
  int t = threadIdx.x, i = blockIdx.x * 256 + t;
  s[t] = (i < n) ? cnt[i] : 0;
  __syncthreads();
  for (int off = 128; off > 0; off >>= 1) {
    if (t < off) s[t] += s[t + off];
    __syncthreads();
  }
  if (t == 0) bsum[blockIdx.x] = s[0];
}
__global__ void k_scan_small(int* bsum, int n) {
  __shared__ int s[256];
  int t = threadIdx.x;
  int orig = (t < n) ? bsum[t] : 0;
  s[t] = orig;
  __syncthreads();
  for (int off = 1; off < 256; off <<= 1) {
    int v = (t >= off) ? s[t - off] : 0;
    __syncthreads();
    s[t] += v;
    __syncthreads();
  }
  if (t < n) bsum[t] = s[t] - orig;  // exclusive
}
__global__ void k_rowptr(const int* __restrict__ cnt, const int* __restrict__ bsum,
                         int* __restrict__ rowptr, float* __restrict__ invc, int n, int total) {
  __shared__ int s[256];
  int t = threadIdx.x, i = blockIdx.x * 256 + t;
  int c = (i < n) ? cnt[i] : 0;
  s[t] = c;
  __syncthreads();
  for (int off = 1; off < 256; off <<= 1) {
    int v = (t >= off) ? s[t - off] : 0;
    __syncthreads();
    s[t] += v;
    __syncthreads();
  }
  if (i < n) {
    rowptr[i] = bsum[blockIdx.x] + s[t] - c;   // exclusive
    invc[i] = 1.0f / (float)(c > 1 ? c : 1);
  }
  if (i == 0) rowptr[n] = total;
}
__global__ void k_scatter(const int* __restrict__ ei, const int* __restrict__ rowptr,
                          int* __restrict__ cursor, int* __restrict__ perm) {
  int e = blockIdx.x * 256 + threadIdx.x;
  int d = ei[N_EDGES + e];
  int srcn = ei[e];
  int pos = rowptr[d] + atomicAdd(&cursor[d], 1);
  perm[pos] = srcn;
}
__global__ void k_gstart(const int* __restrict__ batch, int* __restrict__ gstart) {
  int t = threadIdx.x;
  if (t <= NGRAPH) {
    int lo = 0, hi = N_NODES;
    while (lo < hi) { int mid = (lo + hi) >> 1; if (batch[mid] < t) lo = mid + 1; else hi = mid; }
    gstart[t] = lo;
  }
}

// ---------------- f32 -> bf16 convert ----------------
__global__ void k_f2b(const float* __restrict__ in, u16* __restrict__ out, int n4) {
  int i = blockIdx.x * 256 + threadIdx.x;
  if (i < n4) {
    float4 v = ((const float4*)in)[i];
    u32 lo = (u32)f2bf(v.x) | ((u32)f2bf(v.y) << 16);
    u32 hi = (u32)f2bf(v.z) | ((u32)f2bf(v.w) << 16);
    ((uint2*)out)[i] = make_uint2(lo, hi);
  }
}
__global__ void k_f2b6(const float* __restrict__ s0, u16* __restrict__ d0,
                       const float* __restrict__ s1, u16* __restrict__ d1,
                       const float* __restrict__ s2, u16* __restrict__ d2,
                       const float* __restrict__ s3, u16* __restrict__ d3,
                       const float* __restrict__ s4, u16* __restrict__ d4,
                       const float* __restrict__ s5, u16* __restrict__ d5) {
  int i = blockIdx.x * 256 + threadIdx.x;
  const float* s; u16* d; int off;
  if (i < 8192)       { s = s0; d = d0; off = i; }
  else if (i < 16384) { s = s1; d = d1; off = i - 8192; }
  else if (i < 32768) { s = s2; d = d2; off = i - 16384; }
  else if (i < 49152) { s = s3; d = d3; off = i - 32768; }
  else if (i < 57344) { s = s4; d = d4; off = i - 49152; }
  else                { s = s5; d = d5; off = i - 57344; }
  float4 v = ((const float4*)s)[off];
  u32 lo = (u32)f2bf(v.x) | ((u32)f2bf(v.y) << 16);
  u32 hi = (u32)f2bf(v.z) | ((u32)f2bf(v.w) << 16);
  ((uint2*)(d))[off] = make_uint2(lo, hi);
}

// ---------------- CSR mean aggregation, high-MLP ----------------
// 32 B/lane slots; 16 edges in flight per wave.
// MODE 0: out = mean -> bf16.  MODE 1 (fused SAGE3): out = mean + Radd -> bf16.
template <int D, int MODE>
__global__ __launch_bounds__(256) void k_agg(const u16* __restrict__ x, u16* __restrict__ outp,
                                             const int* __restrict__ rowptr,
                                             const int* __restrict__ perm,
                                             const float* __restrict__ invc,
                                             const u16* __restrict__ Radd, int nn) {
  constexpr int LPR = D / 16;        // lanes per row (8 for D=128, 16 for D=256)
  constexpr int SLOTS = 64 / LPR;    // concurrent edges (8 / 4)
  constexpr int UNROLL = 16 / SLOTS; // edges in flight = 16 per wave
  int wv = threadIdx.x >> 6, lane = threadIdx.x & 63;
  int node = blockIdx.x * 4 + wv;
  if (node >= nn) return;
  int s = rowptr[node], e = rowptr[node + 1];
  int slot = lane / LPR, lsub = lane % LPR;
  float acc[16];
#pragma unroll
  for (int i = 0; i < 16; ++i) acc[i] = 0.f;
  const u16* xl = x + lsub * 16;

  int p = s + slot;
  for (; p + (UNROLL - 1) * SLOTS < e; p += 16) {
    int srcs[UNROLL];
#pragma unroll
    for (int k = 0; k < UNROLL; ++k) srcs[k] = perm[p + k * SLOTS];
    uint4 v0[UNROLL], v1[UNROLL];
#pragma unroll
    for (int k = 0; k < UNROLL; ++k) {
      const uint4* rp = (const uint4*)(xl + (size_t)srcs[k] * D);
      v0[k] = rp[0];
      v1[k] = rp[1];
    }
#pragma unroll
    for (int k = 0; k < UNROLL; ++k) {
      u32 w[8] = {v0[k].x, v0[k].y, v0[k].z, v0[k].w, v1[k].x, v1[k].y, v1[k].z, v1[k].w};
#pragma unroll
      for (int j = 0; j < 8; ++j) {
        acc[2 * j] += __builtin_bit_cast(float, w[j] << 16);
        acc[2 * j + 1] += __builtin_bit_cast(float, w[j] & 0xffff0000u);
      }
    }
  }
  for (; p < e; p += SLOTS) {
    int src = perm[p];
    const uint4* rp = (const uint4*)(xl + (size_t)src * D);
    uint4 a = rp[0], b = rp[1];
    u32 w[8] = {a.x, a.y, a.z, a.w, b.x, b.y, b.z, b.w};
#pragma unroll
    for (int j = 0; j < 8; ++j) {
      acc[2 * j] += __builtin_bit_cast(float, w[j] << 16);
      acc[2 * j + 1] += __builtin_bit_cast(float, w[j] & 0xffff0000u);
    }
  }

  // cross-slot butterfly (slot bits of the lane id)
#pragma unroll
  for (int i = 0; i < 16; ++i) {
    if (SLOTS == 8) acc[i] += __shfl_xor(acc[i], 8, 64);
    acc[i] += __shfl_xor(acc[i], 16, 64);
    acc[i] += __shfl_xor(acc[i], 32, 64);
  }

  if (slot == 0) {
    float iv = invc[node];
    float v[16];
#pragma unroll
    for (int i = 0; i < 16; ++i) v[i] = acc[i] * iv;
    if (MODE == 1) {
      const uint4* rr = (const uint4*)(Radd + (size_t)node * D + lsub * 16);
      uint4 a = rr[0], b = rr[1];
      u32 w[8] = {a.x, a.y, a.z, a.w, b.x, b.y, b.z, b.w};
#pragma unroll
      for (int j = 0; j < 8; ++j) {
        v[2 * j] += __builtin_bit_cast(float, w[j] << 16);
        v[2 * j + 1] += __builtin_bit_cast(float, w[j] & 0xffff0000u);
      }
    }
    u32 wpk[8];
#pragma unroll
    for (int i = 0; i < 8; ++i)
      wpk[i] = (u32)f2bf(v[2 * i]) | ((u32)f2bf(v[2 * i + 1]) << 16);
    uint4* o = (uint4*)(outp + (size_t)node * D + lsub * 16);
    o[0] = make_uint4(wpk[0], wpk[1], wpk[2], wpk[3]);
    o[1] = make_uint4(wpk[4], wpk[5], wpk[6], wpk[7]);
  }
}

// ---------------- bf16 MFMA GEMM:  out = epilogue(A1@W1^T + A2@W2^T) ----------------
// EPI 0: +bias, relu -> bf16 (out1, stride OUTW)
// EPI 3: dual-output: col<128 -> out1 (plain bf16, stride 128); col>=128 -> out2 (+bias, bf16, stride 128)
template <int OUTW, int EPI>
__global__ __launch_bounds__(256) void k_gemm(const u16* __restrict__ A1, const u16* __restrict__ W1, int K1,
                                              const u16* __restrict__ A2, const u16* __restrict__ W2, int K2,
                                              const float* __restrict__ bias,
                                              u16* __restrict__ out1, u16* __restrict__ out2, int M) {
  __shared__ u16 lsA[128 * 64];
  __shared__ u16 lsB[128 * 64];
  const int tid = threadIdx.x, lane = tid & 63, wv = tid >> 6;
  const int wm = wv >> 1, wn = wv & 1;
  const int row0 = blockIdx.x * 128, col0 = blockIdx.y * 128;

  floatx4 acc[4][4];
#pragma unroll
  for (int r = 0; r < 4; ++r)
#pragma unroll
    for (int c = 0; c < 4; ++c) acc[r][c] = 0.f;

  for (int seg = 0; seg < 2; ++seg) {
    const u16* A = seg ? A2 : A1;
    const u16* Wm = seg ? W2 : W1;
    const int K = seg ? K2 : K1;
    if (K == 0) continue;
    for (int k0 = 0; k0 < K; k0 += 64) {
      __syncthreads();
#pragma unroll
      for (int i = 0; i < 4; ++i) {
        int chunk = i * 256 + tid;
        int r = chunk >> 3;
        int kc = chunk & 7;
        int kcs = kc ^ (r & 7);        // pre-swizzle SOURCE, linear LDS dest
        int grow = row0 + r;
        grow = grow < M ? grow : M - 1;
        gld16(A + (size_t)grow * K + (k0 + kcs * 8), lsA + (size_t)(i * 256 + wv * 64) * 8);
        int wr = col0 + r;
        gld16(Wm + (size_t)wr * K + (k0 + kcs * 8), lsB + (size_t)(i * 256 + wv * 64) * 8);
      }
      __syncthreads();
#pragma unroll
      for (int kk = 0; kk < 2; ++kk) {
        bf16x8 af[4], bb[4];
        int kc = kk * 4 + (lane >> 4);
#pragma unroll
        for (int r = 0; r < 4; ++r) {
          int row = wm * 64 + r * 16 + (lane & 15);
          af[r] = __builtin_bit_cast(bf16x8, *(const short8*)(lsA + row * 64 + ((kc ^ (row & 7)) << 3)));
        }
#pragma unroll
        for (int c = 0; c < 4; ++c) {
          int row = wn * 64 + c * 16 + (lane & 15);
          bb[c] = __builtin_bit_cast(bf16x8, *(const short8*)(lsB + row * 64 + ((kc ^ (row & 7)) << 3)));
        }
#pragma unroll
        for (int r = 0; r < 4; ++r)
#pragma unroll
          for (int c = 0; c < 4; ++c)
            acc[r][c] = __builtin_amdgcn_mfma_f32_16x16x32_bf16(af[r], bb[c], acc[r][c], 0, 0, 0);
      }
    }
  }

#pragma unroll
  for (int r = 0; r < 4; ++r) {
    int rowb = row0 + wm * 64 + r * 16 + ((lane >> 4) << 2);
#pragma unroll
    for (int c = 0; c < 4; ++c) {
      int col = col0 + wn * 64 + c * 16 + (lane & 15);
#pragma unroll
      for (int j = 0; j < 4; ++j) {
        int gr = rowb + j;
        if (gr < M) {
          float v = acc[r][c][j];
          if (EPI == 0) {
            v += bias[col];
            v = v > 0.f ? v : 0.f;
            out1[(size_t)gr * OUTW + col] = f2bf(v);
          } else {  // EPI == 3
            if (col < 128) {
              out1[(size_t)gr * 128 + col] = f2bf(v);
            } else {
              v += bias[col - 128];
              out2[(size_t)gr * 128 + (col - 128)] = f2bf(v);
            }
          }
        }
      }
    }
  }
}

// ---------------- global mean pool, phase 1: run-length partial sums (bf16 in) ----------------
__global__ __launch_bounds__(256) void k_pool_part(const u16* __restrict__ h3,
                                                   const int* __restrict__ batch,
                                                   float* __restrict__ gsum) {
  __shared__ int sb[64];
  int t = threadIdx.x;
  int n0 = blockIdx.x * 64;
  if (t < 64) sb[t] = batch[n0 + t];
  __syncthreads();
  int col = t & 127, sub = t >> 7;
  float acc = 0.f;
  int curg = -1;
  for (int i = sub; i < 64; i += 2) {
    int g = sb[i];
    if (g != curg) {
      if (curg >= 0) atomicAdd(&gsum[curg * 128 + col], acc);
      curg = g;
      acc = 0.f;
    }
    acc += bf2f(h3[(size_t)(n0 + i) * 128 + col]);
  }
  if (curg >= 0) atomicAdd(&gsum[curg * 128 + col], acc);
}

// ---------------- per-graph tail: mean finalize + v-proj chain + LayerNorm ----------------
__global__ __launch_bounds__(256) void k_tail(const float* __restrict__ gsum, const int* __restrict__ gstart,
                                              const float* __restrict__ Wv,
                                              const float* __restrict__ bv, const float* __restrict__ ipw,
                                              const float* __restrict__ ipb, const float* __restrict__ outw,
                                              const float* __restrict__ outb, const float* __restrict__ lng,
                                              const float* __restrict__ lnb, float* __restrict__ dout,
                                              float* __restrict__ eout) {
  __shared__ float sa[256], sb[256];
  __shared__ float s_mu, s_var;
  int b = blockIdx.x, t = threadIdx.x;
  if (t < 128) {
    int cg = gstart[b + 1] - gstart[b];
    float mean = gsum[b * 128 + t] / (float)(cg > 1 ? cg : 1);
    sa[t] = mean;
    dout[b * 128 + t] = mean;   // output 0: graph_vec
  }
  __syncthreads();
  float val = bv[t];
  for (int k = 0; k < 128; ++k) val += sa[k] * Wv[t * 128 + k];
  sb[t] = val;
  __syncthreads();
  float vv = ipb[512 + t];
  for (int k = 0; k < 256; ++k) vv += sb[k] * ipw[(size_t)(512 + t) * 256 + k];
  sa[t] = vv;
  __syncthreads();
  float at = outb[t];
  for (int k = 0; k < 256; ++k) at += sa[k] * outw[t * 256 + k];
  sb[t] = at;
  __syncthreads();
  for (int off = 128; off > 0; off >>= 1) {
    if (t < off) sb[t] += sb[t + off];
    __syncthreads();
  }
  if (t == 0) s_mu = sb[0] * (1.0f / 256.0f);
  __syncthreads();
  float d = at - s_mu;
  sb[t] = d * d;
  __syncthreads();
  for (int off = 128; off > 0; off >>= 1) {
    if (t < off) sb[t] += sb[t + off];
    __syncthreads();
  }
  if (t == 0) s_var = sb[0] * (1.0f / 256.0f);
  __syncthreads();
  float r = 1.0f / sqrtf(s_var + 1e-5f);
  eout[(size_t)b * 256 + t] = d * r * lng[t] + lnb[t];
}

// ---------------- broadcast per-graph embedding to nodes ----------------
__global__ void k_scat_out(const float* __restrict__ eb, const int* __restrict__ batch,
                           float* __restrict__ dout) {
  int i = blockIdx.x * 256 + threadIdx.x;
  int n = i >> 6, q = i & 63;
  float4 v = ((const float4*)eb)[(size_t)batch[n] * 64 + q];
  ((float4*)(dout + NGRAPH * 128))[i] = v;
}

// ---------------- launch ----------------
extern "C" void kernel_launch(void* const* d_in, const int* in_sizes, int n_in,
                              void* d_out, int out_size, void* d_ws, size_t ws_size,
                              hipStream_t stream) {
  (void)in_sizes; (void)n_in; (void)out_size; (void)ws_size;
  const float* x_bb = (const float*)d_in[0];
  const float* W1l = (const float*)d_in[2];
  const float* b1l = (const float*)d_in[3];
  const float* W1r = (const float*)d_in[4];
  const float* W2l = (const float*)d_in[5];
  const float* b2l = (const float*)d_in[6];
  const float* W2r = (const float*)d_in[7];
  const float* W3l = (const float*)d_in[8];
  const float* b3l = (const float*)d_in[9];
  const float* W3r = (const float*)d_in[10];
  const float* Wv = (const float*)d_in[15];
  const float* bv = (const float*)d_in[16];
  const float* ipw = (const float*)d_in[17];
  const float* ipb = (const float*)d_in[18];
  const float* outw = (const float*)d_in[19];
  const float* outb = (const float*)d_in[20];
  const float* lng = (const float*)d_in[21];
  const float* lnb = (const float*)d_in[22];
  const int* ei = (const int*)d_in[23];
  const int* batch = (const int*)d_in[24];
  float* dout = (float*)d_out;
  char* ws = (char*)d_ws;

  constexpr size_t O_W1L = 0;
  constexpr size_t O_W1R = O_W1L + 256 * 128 * 2;
  constexpr size_t O_W2L = O_W1R + 256 * 128 * 2;
  constexpr size_t O_W2R = O_W2L + 256 * 256 * 2;
  constexpr size_t O_W3L = O_W2R + 256 * 256 * 2;   // stacked [W3l;W3r] = [256,256] contiguous
  constexpr size_t O_W3R = O_W3L + 128 * 256 * 2;
  constexpr size_t O_XB = O_W3R + 128 * 256 * 2;                      // bf16 [N,128] xb -> later Pb
  constexpr size_t O_MEAN1 = O_XB + (size_t)N_NODES * 128 * 2;       // bf16 [N,128] mean1 -> later R
  constexpr size_t O_H1 = O_MEAN1 + (size_t)N_NODES * 128 * 2;       // bf16 [N,256]
  constexpr size_t O_MEAN2 = O_H1 + (size_t)N_NODES * 256 * 2;       // bf16 [N,256] mean2 -> later h3(bf16 [N,128])
  constexpr size_t O_H2 = O_MEAN2 + (size_t)N_NODES * 256 * 2;       // bf16 [N,256]
  constexpr size_t O_E = O_H2 + (size_t)N_NODES * 256 * 2;           // f32 [64,256]
  constexpr size_t O_CNT = O_E + 64 * 256 * 4;                       // cnt | cursor | gsum contiguous (zeroed together)
  constexpr size_t O_CUR = O_CNT + (size_t)N_NODES * 4;
  constexpr size_t O_GSUM = O_CUR + (size_t)N_NODES * 4;             // f32 [64,128]
  constexpr size_t O_RP = O_GSUM + 64 * 128 * 4;
  constexpr size_t O_INVC = O_RP + (size_t)(N_NODES + 64) * 4;
  constexpr size_t O_BSUM = O_INVC + (size_t)N_NODES * 4;
  constexpr size_t O_GST = O_BSUM + 1024;
  constexpr size_t O_PERM = O_GST + 512;

  u16* w1l = (u16*)(ws + O_W1L);  u16* w1r = (u16*)(ws + O_W1R);
  u16* w2l = (u16*)(ws + O_W2L);  u16* w2r = (u16*)(ws + O_W2R);
  u16* w3s = (u16*)(ws + O_W3L);  u16* w3r = (u16*)(ws + O_W3R);
  u16* xb = (u16*)(ws + O_XB);
  u16* mean1 = (u16*)(ws + O_MEAN1);
  u16* h1 = (u16*)(ws + O_H1);
  u16* mean2 = (u16*)(ws + O_MEAN2);
  u16* h2 = (u16*)(ws + O_H2);
  u16* Pb = (u16*)(ws + O_XB);       // reuse xb region
  u16* Rb = (u16*)(ws + O_MEAN1);    // reuse mean1 region
  u16* h3b = (u16*)(ws + O_MEAN2);   // reuse mean2 region
  float* eb = (float*)(ws + O_E);
  int* cnt = (int*)(ws + O_CNT);
  int* cursor = (int*)(ws + O_CUR);
  float* gsum = (float*)(ws + O_GSUM);
  int* rowptr = (int*)(ws + O_RP);
  float* invc = (float*)(ws + O_INVC);
  int* bsum = (int*)(ws + O_BSUM);
  int* gstart = (int*)(ws + O_GST);
  int* perm = (int*)(ws + O_PERM);

  const int NB = (N_NODES + 255) / 256;  // 157

  // CSR build (cnt + cursor + gsum zeroed in one launch)
  k_zero<<<(2 * N_NODES + 8192 + 255) / 256, 256, 0, stream>>>(cnt, 2 * N_NODES + 8192);
  k_hist<<<N_EDGES / 256, 256, 0, stream>>>(ei, cnt);
  k_blocksum<<<NB, 256, 0, stream>>>(cnt, bsum, N_NODES);
  k_scan_small<<<1, 256, 0, stream>>>(bsum, NB);
  k_rowptr<<<NB, 256, 0, stream>>>(cnt, bsum, rowptr, invc, N_NODES, N_EDGES);
  k_scatter<<<N_EDGES / 256, 256, 0, stream>>>(ei, rowptr, cursor, perm);
  k_gstart<<<1, 128, 0, stream>>>(batch, gstart);

  // bf16 conversions
  k_f2b<<<(N_NODES * 128 / 4 + 255) / 256, 256, 0, stream>>>(x_bb, xb, N_NODES * 128 / 4);
  k_f2b6<<<256, 256, 0, stream>>>(W1l, w1l, W1r, w1r, W2l, w2l, W2r, w2r, W3l, w3s, W3r, w3r);

  dim3 blk(256);
  // SAGE1
  k_agg<128, 0><<<N_NODES / 4, blk, 0, stream>>>(xb, mean1, rowptr, perm, invc, nullptr, N_NODES);
  k_gemm<256, 0><<<dim3(313, 2), blk, 0, stream>>>(mean1, w1l, 128, xb, w1r, 128, b1l, h1, nullptr, N_NODES);
  // SAGE2
  k_agg<256, 0><<<N_NODES / 4, blk, 0, stream>>>(h1, mean2, rowptr, perm, invc, nullptr, N_NODES);
  k_gemm<256, 0><<<dim3(313, 2), blk, 0, stream>>>(mean2, w2l, 256, h1, w2r, 256, b2l, h2, nullptr, N_NODES);
  // SAGE3: one stacked GEMM -> P (bf16) and R = h2@W3r+b3l (bf16); fused agg adds R
  k_gemm<128, 3><<<dim3(313, 2), blk, 0, stream>>>(h2, w3s, 256, nullptr, nullptr, 0, b3l, Pb, Rb, N_NODES);
  k_agg<128, 1><<<N_NODES / 4, blk, 0, stream>>>(Pb, h3b, rowptr, perm, invc, Rb, N_NODES);
  // pool (partial sums) + per-graph tail + broadcast
  k_pool_part<<<N_NODES / 64, blk, 0, stream>>>(h3b, batch, gsum);
  k_tail<<<NGRAPH, blk, 0, stream>>>(gsum, gstart, Wv, bv, ipw, ipb, outw, outb, lng, lnb, dout, eb);
  k_scat_out<<<N_NODES * 64 / 256, blk, 0, stream>>>(eb, batch, dout);
}